// Round 1
// baseline (1416.644 us; speedup 1.0000x reference)
//
#include <hip/hip_runtime.h>
#include <hip/hip_bf16.h>

#define GN_EPS 1e-5f

// ---------------- degree / dinv ----------------
__global__ void k_fill1(float* __restrict__ p, int n) {
    int i = blockIdx.x * blockDim.x + threadIdx.x;
    if (i < n) p[i] = 1.0f;   // self-loop contributes 1 to every node's degree
}

__global__ void k_deg(const int* __restrict__ dst, float* __restrict__ deg, int e) {
    int i = blockIdx.x * blockDim.x + threadIdx.x;
    if (i < e) atomicAdd(&deg[dst[i]], 1.0f);
}

__global__ void k_rsqrt_ip(float* __restrict__ p, int n) {
    int i = blockIdx.x * blockDim.x + threadIdx.x;
    if (i < n) p[i] = rsqrtf(p[i]);   // deg >= 1 always (self-loop)
}

// ---------------- GEMM: Y[n,128] = X[n,128] @ W[128,128] ----------------
// Block: 256 threads, TM=64 rows per block. W (64KB) + padded X tile (33KB) in LDS.
#define TM 64
__global__ __launch_bounds__(256) void k_gemm128(const float* __restrict__ X,
                                                 const float* __restrict__ W,
                                                 float* __restrict__ Y, int nrows) {
    __shared__ float sW[128 * 128];
    __shared__ float sx[TM * 129];   // +1 pad: row strides hit different banks
    const int t = threadIdx.x;

    // load W cooperatively (16384 floats, float4)
    {
        const float4* Wv = (const float4*)W;
        float4* sWv = (float4*)sW;
        #pragma unroll
        for (int i = t; i < 128 * 128 / 4; i += 256) sWv[i] = Wv[i];
    }
    // load X tile (TM rows x 128), guarded, padded stride 129
    const int row0 = blockIdx.x * TM;
    for (int i = t; i < TM * 32; i += 256) {
        int r = i >> 5;
        int c4 = i & 31;
        int grow = row0 + r;
        float4 v = make_float4(0.f, 0.f, 0.f, 0.f);
        if (grow < nrows) v = ((const float4*)(X + (size_t)grow * 128))[c4];
        float* d = &sx[r * 129 + c4 * 4];
        d[0] = v.x; d[1] = v.y; d[2] = v.z; d[3] = v.w;
    }
    __syncthreads();

    const int tx = t & 31;   // col: {tx, tx+32, tx+64, tx+96}
    const int ty = t >> 5;   // rows: ty*8 .. ty*8+7
    float acc[8][4] = {};
    #pragma unroll 4
    for (int k = 0; k < 128; ++k) {
        float w0 = sW[k * 128 + tx];
        float w1 = sW[k * 128 + tx + 32];
        float w2 = sW[k * 128 + tx + 64];
        float w3 = sW[k * 128 + tx + 96];
        #pragma unroll
        for (int i = 0; i < 8; ++i) {
            float a = sx[(ty * 8 + i) * 129 + k];
            acc[i][0] += a * w0;
            acc[i][1] += a * w1;
            acc[i][2] += a * w2;
            acc[i][3] += a * w3;
        }
    }
    #pragma unroll
    for (int i = 0; i < 8; ++i) {
        int grow = row0 + ty * 8 + i;
        if (grow >= nrows) break;
        float* yr = Y + (size_t)grow * 128;
        yr[tx]      = acc[i][0];
        yr[tx + 32] = acc[i][1];
        yr[tx + 64] = acc[i][2];
        yr[tx + 96] = acc[i][3];
    }
}

// ---------------- conv pieces ----------------
// O[i][c] = H[i][c]*dinv[i]^2 + bias[c]   (self-loop term + bias, also zero-inits O)
__global__ void k_selfinit(const float* __restrict__ H, float* __restrict__ O,
                           const float* __restrict__ dinv, const float* __restrict__ bias,
                           int n) {
    size_t idx = (size_t)blockIdx.x * blockDim.x + threadIdx.x;
    size_t tot = (size_t)n * 128;
    if (idx >= tot) return;
    int r = (int)(idx >> 7);
    int c = (int)(idx & 127);
    float di = dinv[r];
    O[idx] = H[idx] * di * di + bias[c];
}

// one wave per edge: O[dst] += H[src] * dinv[src]*dinv[dst]
__global__ __launch_bounds__(256) void k_scatter(const float* __restrict__ H,
                                                 float* __restrict__ O,
                                                 const int* __restrict__ src,
                                                 const int* __restrict__ dst,
                                                 const float* __restrict__ dinv,
                                                 int nedges) {
    int e = blockIdx.x * (blockDim.x >> 6) + (threadIdx.x >> 6);
    if (e >= nedges) return;
    int lane = threadIdx.x & 63;
    int s = src[e], d = dst[e];
    float nrm = dinv[s] * dinv[d];
    const float* hs = H + (size_t)s * 128;
    float* od = O + (size_t)d * 128;
    atomicAdd(&od[lane],      hs[lane]      * nrm);
    atomicAdd(&od[lane + 64], hs[lane + 64] * nrm);
}

// ---------------- GraphNorm ----------------
// S[0..127] = column sums, S[128..255] = column sums of squares
__global__ __launch_bounds__(256) void k_stats(const float* __restrict__ H,
                                               float* __restrict__ S, int n) {
    int c = threadIdx.x & 127;
    int half = threadIdx.x >> 7;   // 0 or 1
    float sum = 0.f, ss = 0.f;
    for (int r = blockIdx.x * 2 + half; r < n; r += gridDim.x * 2) {
        float v = H[(size_t)r * 128 + c];
        sum += v;
        ss += v * v;
    }
    __shared__ float ls[256], lss[256];
    ls[threadIdx.x] = sum;
    lss[threadIdx.x] = ss;
    __syncthreads();
    if (threadIdx.x < 128) {
        atomicAdd(&S[c],       ls[threadIdx.x] + ls[threadIdx.x + 128]);
        atomicAdd(&S[128 + c], lss[threadIdx.x] + lss[threadIdx.x + 128]);
    }
}

// in-place: H = relu((H - a*m) * rsqrt(var+eps) * w + b)
__global__ void k_gnorm_relu(float* __restrict__ H, const float* __restrict__ S,
                             const float* __restrict__ w, const float* __restrict__ b,
                             const float* __restrict__ alpha, int n) {
    size_t idx = (size_t)blockIdx.x * blockDim.x + threadIdx.x;
    size_t tot = (size_t)n * 128;
    if (idx >= tot) return;
    int c = (int)(idx & 127);
    float inv_n = 1.0f / (float)n;
    float m = S[c] * inv_n;
    float eh2 = S[128 + c] * inv_n;
    float a = alpha[c];
    float var = eh2 - (2.0f * a - a * a) * m * m;   // E[(h-am)^2]
    float scale = rsqrtf(var + GN_EPS) * w[c];
    float v = (H[idx] - a * m) * scale + b[c];
    H[idx] = v > 0.f ? v : 0.f;
}

// ---------------- output projection: out[n,2] = H[n,128] @ Wo[128,2] + bo ----------------
__global__ __launch_bounds__(256) void k_outproj(const float* __restrict__ H,
                                                 const float* __restrict__ Wo,
                                                 const float* __restrict__ bo,
                                                 float* __restrict__ out, int n) {
    int row = blockIdx.x * (blockDim.x >> 6) + (threadIdx.x >> 6);
    if (row >= n) return;
    int lane = threadIdx.x & 63;
    const float* hr = H + (size_t)row * 128;
    float h0 = hr[lane], h1 = hr[lane + 64];
    float a0 = h0 * Wo[2 * lane]     + h1 * Wo[2 * (lane + 64)];
    float a1 = h0 * Wo[2 * lane + 1] + h1 * Wo[2 * (lane + 64) + 1];
    #pragma unroll
    for (int off = 32; off; off >>= 1) {
        a0 += __shfl_down(a0, off);
        a1 += __shfl_down(a1, off);
    }
    if (lane == 0) {
        out[(size_t)row * 2]     = a0 + bo[0];
        out[(size_t)row * 2 + 1] = a1 + bo[1];
    }
}

extern "C" void kernel_launch(void* const* d_in, const int* in_sizes, int n_in,
                              void* d_out, int out_size, void* d_ws, size_t ws_size,
                              hipStream_t stream) {
    const float* x    = (const float*)d_in[0];
    const int*   ei   = (const int*)  d_in[1];
    const float* W1   = (const float*)d_in[2];
    const float* b1   = (const float*)d_in[3];
    const float* W2   = (const float*)d_in[4];
    const float* b2   = (const float*)d_in[5];
    const float* W3   = (const float*)d_in[6];
    const float* b3   = (const float*)d_in[7];
    const float* gn1w = (const float*)d_in[8];
    const float* gn1b = (const float*)d_in[9];
    const float* gn1a = (const float*)d_in[10];
    const float* gn2w = (const float*)d_in[11];
    const float* gn2b = (const float*)d_in[12];
    const float* gn2a = (const float*)d_in[13];
    const float* Wout = (const float*)d_in[14];
    const float* bout = (const float*)d_in[15];
    float* out = (float*)d_out;

    const int n = in_sizes[0] / 128;
    const int e = in_sizes[1] / 2;
    const int* srcI = ei;
    const int* dstI = ei + e;

    float* bufA = (float*)d_ws;
    float* bufB = bufA + (size_t)n * 128;
    float* dinv = bufB + (size_t)n * 128;
    float* S    = dinv + n;   // 256 floats

    const int elemGrid = (int)(((size_t)n * 128 + 255) / 256);

    // degree -> dinv (shared by all three convs)
    k_fill1<<<(n + 255) / 256, 256, 0, stream>>>(dinv, n);
    k_deg<<<(e + 255) / 256, 256, 0, stream>>>(dstI, dinv, e);
    k_rsqrt_ip<<<(n + 255) / 256, 256, 0, stream>>>(dinv, n);

    auto conv = [&](const float* xin, const float* W, const float* bias) {
        k_gemm128<<<(n + TM - 1) / TM, 256, 0, stream>>>(xin, W, bufA, n);
        k_selfinit<<<elemGrid, 256, 0, stream>>>(bufA, bufB, dinv, bias, n);
        k_scatter<<<(e + 3) / 4, 256, 0, stream>>>(bufA, bufB, srcI, dstI, dinv, e);
    };

    // layer 1
    conv(x, W1, b1);
    hipMemsetAsync(S, 0, 256 * sizeof(float), stream);
    k_stats<<<512, 256, 0, stream>>>(bufB, S, n);
    k_gnorm_relu<<<elemGrid, 256, 0, stream>>>(bufB, S, gn1w, gn1b, gn1a, n);

    // layer 2
    conv(bufB, W2, b2);
    hipMemsetAsync(S, 0, 256 * sizeof(float), stream);
    k_stats<<<512, 256, 0, stream>>>(bufB, S, n);
    k_gnorm_relu<<<elemGrid, 256, 0, stream>>>(bufB, S, gn2w, gn2b, gn2a, n);

    // layer 3 (no norm) + output projection
    conv(bufB, W3, b3);
    k_outproj<<<(n + 3) / 4, 256, 0, stream>>>(bufB, Wout, bout, out, n);
}

// Round 2
// 683.905 us; speedup vs baseline: 2.0714x; 2.0714x over previous
//
#include <hip/hip_runtime.h>
#include <hip/hip_bf16.h>

#define GN_EPS 1e-5f

// ---------------- CSR build ----------------
__global__ void k_degi(const int* __restrict__ dst, int* __restrict__ degi, int e) {
    int i = blockIdx.x * blockDim.x + threadIdx.x;
    if (i < e) atomicAdd(&degi[dst[i]], 1);
}

// single-block exclusive scan of degi -> rowptr/cursor; also dinv = rsqrt(deg+1)
__global__ __launch_bounds__(1024) void k_scan(const int* __restrict__ degi,
                                               int* __restrict__ rowptr,
                                               int* __restrict__ cursor,
                                               float* __restrict__ dinv, int n) {
    __shared__ int wsum[16];
    __shared__ int carry_s;
    const int lane = threadIdx.x & 63;
    const int wid = threadIdx.x >> 6;
    if (threadIdx.x == 0) carry_s = 0;
    __syncthreads();
    for (int base = 0; base < n; base += 1024) {
        int i = base + threadIdx.x;
        int v = (i < n) ? degi[i] : 0;
        // wave-inclusive scan (shfl, no barriers)
        int x = v;
        #pragma unroll
        for (int off = 1; off < 64; off <<= 1) {
            int t = __shfl_up(x, off);
            if (lane >= off) x += t;
        }
        if (lane == 63) wsum[wid] = x;
        __syncthreads();
        if (wid == 0 && lane < 16) {
            int y = wsum[lane];
            #pragma unroll
            for (int off = 1; off < 16; off <<= 1) {
                int t = __shfl_up(y, off, 16);
                if (lane >= off) y += t;
            }
            wsum[lane] = y;   // inclusive wave sums
        }
        __syncthreads();
        int waveoff = (wid == 0) ? 0 : wsum[wid - 1];
        int incl = x + waveoff + carry_s;
        if (i < n) {
            int excl = incl - v;
            rowptr[i] = excl;
            cursor[i] = excl;
            dinv[i] = rsqrtf((float)(v + 1));   // +1 self-loop
        }
        __syncthreads();
        if (threadIdx.x == 1023) carry_s = incl;
        __syncthreads();
    }
    if (threadIdx.x == 0) rowptr[n] = carry_s;
}

__global__ void k_fill(const int* __restrict__ src, const int* __restrict__ dst,
                       int* __restrict__ cursor, int* __restrict__ csr_src, int e) {
    int i = blockIdx.x * blockDim.x + threadIdx.x;
    if (i < e) {
        int d = dst[i];
        int pos = atomicAdd(&cursor[d], 1);
        csr_src[pos] = src[i];
    }
}

// ---------------- GEMM: Y[n,128] = X[n,128] @ W[128,128] ----------------
#define TM 64
__global__ __launch_bounds__(256) void k_gemm128(const float* __restrict__ X,
                                                 const float* __restrict__ W,
                                                 float* __restrict__ Y, int nrows) {
    __shared__ float sW[128 * 128];
    __shared__ float sx[TM * 129];
    const int t = threadIdx.x;
    {
        const float4* Wv = (const float4*)W;
        float4* sWv = (float4*)sW;
        #pragma unroll
        for (int i = t; i < 128 * 128 / 4; i += 256) sWv[i] = Wv[i];
    }
    const int row0 = blockIdx.x * TM;
    for (int i = t; i < TM * 32; i += 256) {
        int r = i >> 5;
        int c4 = i & 31;
        int grow = row0 + r;
        float4 v = make_float4(0.f, 0.f, 0.f, 0.f);
        if (grow < nrows) v = ((const float4*)(X + (size_t)grow * 128))[c4];
        float* d = &sx[r * 129 + c4 * 4];
        d[0] = v.x; d[1] = v.y; d[2] = v.z; d[3] = v.w;
    }
    __syncthreads();

    const int tx = t & 31;
    const int ty = t >> 5;
    float acc[8][4] = {};
    #pragma unroll 4
    for (int k = 0; k < 128; ++k) {
        float w0 = sW[k * 128 + tx];
        float w1 = sW[k * 128 + tx + 32];
        float w2 = sW[k * 128 + tx + 64];
        float w3 = sW[k * 128 + tx + 96];
        #pragma unroll
        for (int i = 0; i < 8; ++i) {
            float a = sx[(ty * 8 + i) * 129 + k];
            acc[i][0] += a * w0;
            acc[i][1] += a * w1;
            acc[i][2] += a * w2;
            acc[i][3] += a * w3;
        }
    }
    #pragma unroll
    for (int i = 0; i < 8; ++i) {
        int grow = row0 + ty * 8 + i;
        if (grow >= nrows) break;
        float* yr = Y + (size_t)grow * 128;
        yr[tx]      = acc[i][0];
        yr[tx + 32] = acc[i][1];
        yr[tx + 64] = acc[i][2];
        yr[tx + 96] = acc[i][3];
    }
}

// ---------------- pull-gather conv (replaces selfinit + scatter) ----------------
// One wave per node: O[i] = H[i]*dinv[i]^2 + bias + sum_{s in in(i)} H[s]*dinv[s]*dinv[i]
__global__ __launch_bounds__(256) void k_gather(const float* __restrict__ H,
                                                float* __restrict__ O,
                                                const int* __restrict__ rowptr,
                                                const int* __restrict__ csr_src,
                                                const float* __restrict__ dinv,
                                                const float* __restrict__ bias, int n) {
    int node = blockIdx.x * 4 + (threadIdx.x >> 6);
    if (node >= n) return;
    int lane = threadIdx.x & 63;
    float di = dinv[node];
    const float* hn = H + (size_t)node * 128;
    float acc0 = hn[lane]      * di * di + bias[lane];
    float acc1 = hn[lane + 64] * di * di + bias[lane + 64];
    int j = rowptr[node];
    const int end = rowptr[node + 1];
    for (; j + 1 < end; j += 2) {
        int s0 = csr_src[j], s1 = csr_src[j + 1];
        float n0 = dinv[s0] * di, n1 = dinv[s1] * di;
        const float* h0 = H + (size_t)s0 * 128;
        const float* h1 = H + (size_t)s1 * 128;
        acc0 += h0[lane] * n0;
        acc1 += h0[lane + 64] * n0;
        acc0 += h1[lane] * n1;
        acc1 += h1[lane + 64] * n1;
    }
    if (j < end) {
        int s = csr_src[j];
        float nn = dinv[s] * di;
        const float* h = H + (size_t)s * 128;
        acc0 += h[lane] * nn;
        acc1 += h[lane + 64] * nn;
    }
    float* od = O + (size_t)node * 128;
    od[lane]      = acc0;
    od[lane + 64] = acc1;
}

// ---------------- GraphNorm ----------------
__global__ __launch_bounds__(256) void k_stats(const float* __restrict__ H,
                                               float* __restrict__ S, int n) {
    int c = threadIdx.x & 127;
    int half = threadIdx.x >> 7;
    float sum = 0.f, ss = 0.f;
    for (int r = blockIdx.x * 2 + half; r < n; r += gridDim.x * 2) {
        float v = H[(size_t)r * 128 + c];
        sum += v;
        ss += v * v;
    }
    __shared__ float ls[256], lss[256];
    ls[threadIdx.x] = sum;
    lss[threadIdx.x] = ss;
    __syncthreads();
    if (threadIdx.x < 128) {
        atomicAdd(&S[c],       ls[threadIdx.x] + ls[threadIdx.x + 128]);
        atomicAdd(&S[128 + c], lss[threadIdx.x] + lss[threadIdx.x + 128]);
    }
}

__global__ void k_gnorm_relu(float* __restrict__ H, const float* __restrict__ S,
                             const float* __restrict__ w, const float* __restrict__ b,
                             const float* __restrict__ alpha, int n) {
    size_t idx = (size_t)blockIdx.x * blockDim.x + threadIdx.x;
    size_t tot = (size_t)n * 128;
    if (idx >= tot) return;
    int c = (int)(idx & 127);
    float inv_n = 1.0f / (float)n;
    float m = S[c] * inv_n;
    float eh2 = S[128 + c] * inv_n;
    float a = alpha[c];
    float var = eh2 - (2.0f * a - a * a) * m * m;
    float scale = rsqrtf(var + GN_EPS) * w[c];
    float v = (H[idx] - a * m) * scale + b[c];
    H[idx] = v > 0.f ? v : 0.f;
}

// ---------------- output projection ----------------
__global__ __launch_bounds__(256) void k_outproj(const float* __restrict__ H,
                                                 const float* __restrict__ Wo,
                                                 const float* __restrict__ bo,
                                                 float* __restrict__ out, int n) {
    int row = blockIdx.x * (blockDim.x >> 6) + (threadIdx.x >> 6);
    if (row >= n) return;
    int lane = threadIdx.x & 63;
    const float* hr = H + (size_t)row * 128;
    float h0 = hr[lane], h1 = hr[lane + 64];
    float a0 = h0 * Wo[2 * lane]     + h1 * Wo[2 * (lane + 64)];
    float a1 = h0 * Wo[2 * lane + 1] + h1 * Wo[2 * (lane + 64) + 1];
    #pragma unroll
    for (int off = 32; off; off >>= 1) {
        a0 += __shfl_down(a0, off);
        a1 += __shfl_down(a1, off);
    }
    if (lane == 0) {
        out[(size_t)row * 2]     = a0 + bo[0];
        out[(size_t)row * 2 + 1] = a1 + bo[1];
    }
}

extern "C" void kernel_launch(void* const* d_in, const int* in_sizes, int n_in,
                              void* d_out, int out_size, void* d_ws, size_t ws_size,
                              hipStream_t stream) {
    const float* x    = (const float*)d_in[0];
    const int*   ei   = (const int*)  d_in[1];
    const float* W1   = (const float*)d_in[2];
    const float* b1   = (const float*)d_in[3];
    const float* W2   = (const float*)d_in[4];
    const float* b2   = (const float*)d_in[5];
    const float* W3   = (const float*)d_in[6];
    const float* b3   = (const float*)d_in[7];
    const float* gn1w = (const float*)d_in[8];
    const float* gn1b = (const float*)d_in[9];
    const float* gn1a = (const float*)d_in[10];
    const float* gn2w = (const float*)d_in[11];
    const float* gn2b = (const float*)d_in[12];
    const float* gn2a = (const float*)d_in[13];
    const float* Wout = (const float*)d_in[14];
    const float* bout = (const float*)d_in[15];
    float* out = (float*)d_out;

    const int n = in_sizes[0] / 128;
    const int e = in_sizes[1] / 2;
    const int* srcI = ei;
    const int* dstI = ei + e;

    // workspace layout (all 4-byte types)
    float* bufA    = (float*)d_ws;                       // n*128
    float* bufB    = bufA + (size_t)n * 128;             // n*128
    float* dinv    = bufB + (size_t)n * 128;             // n
    float* S       = dinv + n;                           // 256
    int*   degi    = (int*)(S + 256);                    // n
    int*   rowptr  = degi + n;                           // n+1
    int*   cursor  = rowptr + n + 1;                     // n
    int*   csr_src = cursor + n;                         // e

    const int elemGrid = (int)(((size_t)n * 128 + 255) / 256);

    // ---- CSR build (once per call) ----
    hipMemsetAsync(degi, 0, (size_t)n * sizeof(int), stream);
    k_degi<<<(e + 255) / 256, 256, 0, stream>>>(dstI, degi, e);
    k_scan<<<1, 1024, 0, stream>>>(degi, rowptr, cursor, dinv, n);
    k_fill<<<(e + 255) / 256, 256, 0, stream>>>(srcI, dstI, cursor, csr_src, e);

    auto conv = [&](const float* xin, const float* W, const float* bias) {
        k_gemm128<<<(n + TM - 1) / TM, 256, 0, stream>>>(xin, W, bufA, n);
        k_gather<<<(n + 3) / 4, 256, 0, stream>>>(bufA, bufB, rowptr, csr_src, dinv, bias, n);
    };

    // layer 1
    conv(x, W1, b1);
    hipMemsetAsync(S, 0, 256 * sizeof(float), stream);
    k_stats<<<512, 256, 0, stream>>>(bufB, S, n);
    k_gnorm_relu<<<elemGrid, 256, 0, stream>>>(bufB, S, gn1w, gn1b, gn1a, n);

    // layer 2
    conv(bufB, W2, b2);
    hipMemsetAsync(S, 0, 256 * sizeof(float), stream);
    k_stats<<<512, 256, 0, stream>>>(bufB, S, n);
    k_gnorm_relu<<<elemGrid, 256, 0, stream>>>(bufB, S, gn2w, gn2b, gn2a, n);

    // layer 3 + projection
    conv(bufB, W3, b3);
    k_outproj<<<(n + 3) / 4, 256, 0, stream>>>(bufB, Wout, bout, out, n);
}

// Round 3
// 644.411 us; speedup vs baseline: 2.1984x; 1.0613x over previous
//
#include <hip/hip_runtime.h>
#include <hip/hip_bf16.h>

#define GN_EPS 1e-5f

// ---------------- CSR build ----------------
__global__ void k_degi(const int* __restrict__ dst, int* __restrict__ degi, int e) {
    int i = blockIdx.x * blockDim.x + threadIdx.x;
    if (i < e) atomicAdd(&degi[dst[i]], 1);
}

__global__ __launch_bounds__(1024) void k_scan(const int* __restrict__ degi,
                                               int* __restrict__ rowptr,
                                               int* __restrict__ cursor,
                                               float* __restrict__ dinv, int n) {
    __shared__ int wsum[16];
    __shared__ int carry_s;
    const int lane = threadIdx.x & 63;
    const int wid = threadIdx.x >> 6;
    if (threadIdx.x == 0) carry_s = 0;
    __syncthreads();
    for (int base = 0; base < n; base += 1024) {
        int i = base + threadIdx.x;
        int v = (i < n) ? degi[i] : 0;
        int x = v;
        #pragma unroll
        for (int off = 1; off < 64; off <<= 1) {
            int t = __shfl_up(x, off);
            if (lane >= off) x += t;
        }
        if (lane == 63) wsum[wid] = x;
        __syncthreads();
        if (wid == 0 && lane < 16) {
            int y = wsum[lane];
            #pragma unroll
            for (int off = 1; off < 16; off <<= 1) {
                int t = __shfl_up(y, off, 16);
                if (lane >= off) y += t;
            }
            wsum[lane] = y;
        }
        __syncthreads();
        int waveoff = (wid == 0) ? 0 : wsum[wid - 1];
        int incl = x + waveoff + carry_s;
        if (i < n) {
            int excl = incl - v;
            rowptr[i] = excl;
            cursor[i] = excl;
            dinv[i] = rsqrtf((float)(v + 1));
        }
        __syncthreads();
        if (threadIdx.x == 1023) carry_s = incl;
        __syncthreads();
    }
    if (threadIdx.x == 0) rowptr[n] = carry_s;
}

__global__ void k_fill(const int* __restrict__ src, const int* __restrict__ dst,
                       int* __restrict__ cursor, int* __restrict__ csr_src, int e) {
    int i = blockIdx.x * blockDim.x + threadIdx.x;
    if (i < e) {
        int d = dst[i];
        int pos = atomicAdd(&cursor[d], 1);
        csr_src[pos] = src[i];
    }
}

// ---------------- GEMM: Y[n,128] = f(X)[n,128] @ W[128,128] ----------------
// f(X) = relu(X*colscale + colshift) when cs != nullptr (fused GraphNorm+ReLU), else X.
// 256 threads, TM=64 rows/block. Thread = 4 rows x 8 cols register block.
#define TM 64
__global__ __launch_bounds__(256) void k_gemm128(const float* __restrict__ X,
                                                 const float* __restrict__ W,
                                                 float* __restrict__ Y,
                                                 const float* __restrict__ cs,
                                                 const float* __restrict__ cb,
                                                 int nrows) {
    __shared__ float sW[128 * 128];
    __shared__ float sx[TM * 129];
    const int t = threadIdx.x;
    {
        const float4* Wv = (const float4*)W;
        float4* sWv = (float4*)sW;
        #pragma unroll
        for (int i = t; i < 128 * 128 / 4; i += 256) sWv[i] = Wv[i];
    }
    const int row0 = blockIdx.x * TM;
    if (cs) {
        for (int i = t; i < TM * 32; i += 256) {
            int r = i >> 5, c4 = i & 31;
            int grow = row0 + r;
            float4 v = make_float4(0.f, 0.f, 0.f, 0.f);
            if (grow < nrows) v = ((const float4*)(X + (size_t)grow * 128))[c4];
            float4 s4 = ((const float4*)cs)[c4];
            float4 b4 = ((const float4*)cb)[c4];
            v.x = fmaxf(fmaf(v.x, s4.x, b4.x), 0.f);
            v.y = fmaxf(fmaf(v.y, s4.y, b4.y), 0.f);
            v.z = fmaxf(fmaf(v.z, s4.z, b4.z), 0.f);
            v.w = fmaxf(fmaf(v.w, s4.w, b4.w), 0.f);
            float* d = &sx[r * 129 + c4 * 4];
            d[0] = v.x; d[1] = v.y; d[2] = v.z; d[3] = v.w;
        }
    } else {
        for (int i = t; i < TM * 32; i += 256) {
            int r = i >> 5, c4 = i & 31;
            int grow = row0 + r;
            float4 v = make_float4(0.f, 0.f, 0.f, 0.f);
            if (grow < nrows) v = ((const float4*)(X + (size_t)grow * 128))[c4];
            float* d = &sx[r * 129 + c4 * 4];
            d[0] = v.x; d[1] = v.y; d[2] = v.z; d[3] = v.w;
        }
    }
    __syncthreads();

    const int tc = t & 15;   // cols tc*8 .. tc*8+7
    const int tr = t >> 4;   // rows tr*4 .. tr*4+3
    float acc[4][8] = {};
    #pragma unroll 4
    for (int k = 0; k < 128; ++k) {
        float4 w0 = *(const float4*)(sW + k * 128 + tc * 8);
        float4 w1 = *(const float4*)(sW + k * 128 + tc * 8 + 4);
        float x0 = sx[(tr * 4 + 0) * 129 + k];
        float x1 = sx[(tr * 4 + 1) * 129 + k];
        float x2 = sx[(tr * 4 + 2) * 129 + k];
        float x3 = sx[(tr * 4 + 3) * 129 + k];
        acc[0][0] += x0 * w0.x; acc[0][1] += x0 * w0.y; acc[0][2] += x0 * w0.z; acc[0][3] += x0 * w0.w;
        acc[0][4] += x0 * w1.x; acc[0][5] += x0 * w1.y; acc[0][6] += x0 * w1.z; acc[0][7] += x0 * w1.w;
        acc[1][0] += x1 * w0.x; acc[1][1] += x1 * w0.y; acc[1][2] += x1 * w0.z; acc[1][3] += x1 * w0.w;
        acc[1][4] += x1 * w1.x; acc[1][5] += x1 * w1.y; acc[1][6] += x1 * w1.z; acc[1][7] += x1 * w1.w;
        acc[2][0] += x2 * w0.x; acc[2][1] += x2 * w0.y; acc[2][2] += x2 * w0.z; acc[2][3] += x2 * w0.w;
        acc[2][4] += x2 * w1.x; acc[2][5] += x2 * w1.y; acc[2][6] += x2 * w1.z; acc[2][7] += x2 * w1.w;
        acc[3][0] += x3 * w0.x; acc[3][1] += x3 * w0.y; acc[3][2] += x3 * w0.z; acc[3][3] += x3 * w0.w;
        acc[3][4] += x3 * w1.x; acc[3][5] += x3 * w1.y; acc[3][6] += x3 * w1.z; acc[3][7] += x3 * w1.w;
    }
    #pragma unroll
    for (int i = 0; i < 4; ++i) {
        int grow = row0 + tr * 4 + i;
        if (grow >= nrows) continue;
        float* yr = Y + (size_t)grow * 128 + tc * 8;
        *(float4*)(yr)     = make_float4(acc[i][0], acc[i][1], acc[i][2], acc[i][3]);
        *(float4*)(yr + 4) = make_float4(acc[i][4], acc[i][5], acc[i][6], acc[i][7]);
    }
}

// ---------------- pull-gather conv ----------------
// One wave per node: O[i] = H[i]*dinv[i]^2 + bias + sum_{s in in(i)} H[s]*dinv[s]*dinv[i]
__global__ __launch_bounds__(256) void k_gather(const float* __restrict__ H,
                                                float* __restrict__ O,
                                                const int* __restrict__ rowptr,
                                                const int* __restrict__ csr_src,
                                                const float* __restrict__ dinv,
                                                const float* __restrict__ bias, int n) {
    int node = blockIdx.x * 4 + (threadIdx.x >> 6);
    if (node >= n) return;
    int lane = threadIdx.x & 63;
    float di = dinv[node];
    float2 h = ((const float2*)(H + (size_t)node * 128))[lane];
    float2 b = ((const float2*)bias)[lane];
    float2 acc;
    acc.x = h.x * di * di + b.x;
    acc.y = h.y * di * di + b.y;
    int j = rowptr[node];
    const int end = rowptr[node + 1];
    for (; j + 3 < end; j += 4) {
        int s0 = csr_src[j], s1 = csr_src[j + 1], s2 = csr_src[j + 2], s3 = csr_src[j + 3];
        float n0 = dinv[s0] * di, n1 = dinv[s1] * di, n2 = dinv[s2] * di, n3 = dinv[s3] * di;
        float2 v0 = ((const float2*)(H + (size_t)s0 * 128))[lane];
        float2 v1 = ((const float2*)(H + (size_t)s1 * 128))[lane];
        float2 v2 = ((const float2*)(H + (size_t)s2 * 128))[lane];
        float2 v3 = ((const float2*)(H + (size_t)s3 * 128))[lane];
        acc.x += v0.x * n0; acc.y += v0.y * n0;
        acc.x += v1.x * n1; acc.y += v1.y * n1;
        acc.x += v2.x * n2; acc.y += v2.y * n2;
        acc.x += v3.x * n3; acc.y += v3.y * n3;
    }
    for (; j < end; ++j) {
        int s = csr_src[j];
        float nn = dinv[s] * di;
        float2 v = ((const float2*)(H + (size_t)s * 128))[lane];
        acc.x += v.x * nn; acc.y += v.y * nn;
    }
    ((float2*)(O + (size_t)node * 128))[lane] = acc;
}

// ---------------- GraphNorm stats ----------------
__global__ __launch_bounds__(256) void k_stats(const float* __restrict__ H,
                                               float* __restrict__ S, int n) {
    int c = threadIdx.x & 127;
    int half = threadIdx.x >> 7;
    float sum = 0.f, ss = 0.f;
    for (int r = blockIdx.x * 2 + half; r < n; r += gridDim.x * 2) {
        float v = H[(size_t)r * 128 + c];
        sum += v;
        ss += v * v;
    }
    __shared__ float ls[256], lss[256];
    ls[threadIdx.x] = sum;
    lss[threadIdx.x] = ss;
    __syncthreads();
    if (threadIdx.x < 128) {
        atomicAdd(&S[c],       ls[threadIdx.x] + ls[threadIdx.x + 128]);
        atomicAdd(&S[128 + c], lss[threadIdx.x] + lss[threadIdx.x + 128]);
    }
}

// fold S + GraphNorm params into per-column affine: xnorm = x*colscale + colshift (then relu)
__global__ void k_finstats(const float* __restrict__ S,
                           const float* __restrict__ w, const float* __restrict__ b,
                           const float* __restrict__ alpha,
                           float* __restrict__ colscale, float* __restrict__ colshift,
                           int n) {
    int c = threadIdx.x;
    if (c >= 128) return;
    float inv_n = 1.0f / (float)n;
    float m = S[c] * inv_n;
    float eh2 = S[128 + c] * inv_n;
    float a = alpha[c];
    float var = eh2 - (2.0f * a - a * a) * m * m;
    float scale = rsqrtf(var + GN_EPS) * w[c];
    colscale[c] = scale;
    colshift[c] = b[c] - a * m * scale;
}

// ---------------- output projection ----------------
__global__ __launch_bounds__(256) void k_outproj(const float* __restrict__ H,
                                                 const float* __restrict__ Wo,
                                                 const float* __restrict__ bo,
                                                 float* __restrict__ out, int n) {
    int row = blockIdx.x * (blockDim.x >> 6) + (threadIdx.x >> 6);
    if (row >= n) return;
    int lane = threadIdx.x & 63;
    const float* hr = H + (size_t)row * 128;
    float h0 = hr[lane], h1 = hr[lane + 64];
    float a0 = h0 * Wo[2 * lane]     + h1 * Wo[2 * (lane + 64)];
    float a1 = h0 * Wo[2 * lane + 1] + h1 * Wo[2 * (lane + 64) + 1];
    #pragma unroll
    for (int off = 32; off; off >>= 1) {
        a0 += __shfl_down(a0, off);
        a1 += __shfl_down(a1, off);
    }
    if (lane == 0) {
        out[(size_t)row * 2]     = a0 + bo[0];
        out[(size_t)row * 2 + 1] = a1 + bo[1];
    }
}

extern "C" void kernel_launch(void* const* d_in, const int* in_sizes, int n_in,
                              void* d_out, int out_size, void* d_ws, size_t ws_size,
                              hipStream_t stream) {
    const float* x    = (const float*)d_in[0];
    const int*   ei   = (const int*)  d_in[1];
    const float* W1   = (const float*)d_in[2];
    const float* b1   = (const float*)d_in[3];
    const float* W2   = (const float*)d_in[4];
    const float* b2   = (const float*)d_in[5];
    const float* W3   = (const float*)d_in[6];
    const float* b3   = (const float*)d_in[7];
    const float* gn1w = (const float*)d_in[8];
    const float* gn1b = (const float*)d_in[9];
    const float* gn1a = (const float*)d_in[10];
    const float* gn2w = (const float*)d_in[11];
    const float* gn2b = (const float*)d_in[12];
    const float* gn2a = (const float*)d_in[13];
    const float* Wout = (const float*)d_in[14];
    const float* bout = (const float*)d_in[15];
    float* out = (float*)d_out;

    const int n = in_sizes[0] / 128;
    const int e = in_sizes[1] / 2;
    const int* srcI = ei;
    const int* dstI = ei + e;

    float* bufA     = (float*)d_ws;                      // n*128
    float* bufB     = bufA + (size_t)n * 128;            // n*128
    float* dinv     = bufB + (size_t)n * 128;            // n
    float* S        = dinv + n;                          // 256
    float* colscale = S + 256;                           // 128
    float* colshift = colscale + 128;                    // 128
    int*   degi     = (int*)(colshift + 128);            // n
    int*   rowptr   = degi + n;                          // n+1
    int*   cursor   = rowptr + n + 1;                    // n
    int*   csr_src  = cursor + n;                        // e

    // ---- CSR build ----
    hipMemsetAsync(degi, 0, (size_t)n * sizeof(int), stream);
    k_degi<<<(e + 255) / 256, 256, 0, stream>>>(dstI, degi, e);
    k_scan<<<1, 1024, 0, stream>>>(degi, rowptr, cursor, dinv, n);
    k_fill<<<(e + 255) / 256, 256, 0, stream>>>(srcI, dstI, cursor, csr_src, e);

    const int gemmGrid = (n + TM - 1) / TM;

    // layer 1 (no input norm)
    k_gemm128<<<gemmGrid, 256, 0, stream>>>(x, W1, bufA, nullptr, nullptr, n);
    k_gather<<<(n + 3) / 4, 256, 0, stream>>>(bufA, bufB, rowptr, csr_src, dinv, b1, n);
    hipMemsetAsync(S, 0, 256 * sizeof(float), stream);
    k_stats<<<512, 256, 0, stream>>>(bufB, S, n);
    k_finstats<<<1, 128, 0, stream>>>(S, gn1w, gn1b, gn1a, colscale, colshift, n);

    // layer 2 (norm+relu fused into GEMM input load)
    k_gemm128<<<gemmGrid, 256, 0, stream>>>(bufB, W2, bufA, colscale, colshift, n);
    k_gather<<<(n + 3) / 4, 256, 0, stream>>>(bufA, bufB, rowptr, csr_src, dinv, b2, n);
    hipMemsetAsync(S, 0, 256 * sizeof(float), stream);
    k_stats<<<512, 256, 0, stream>>>(bufB, S, n);
    k_finstats<<<1, 128, 0, stream>>>(S, gn2w, gn2b, gn2a, colscale, colshift, n);

    // layer 3 + projection
    k_gemm128<<<gemmGrid, 256, 0, stream>>>(bufB, W3, bufA, colscale, colshift, n);
    k_gather<<<(n + 3) / 4, 256, 0, stream>>>(bufA, bufB, rowptr, csr_src, dinv, b3, n);
    k_outproj<<<(n + 3) / 4, 256, 0, stream>>>(bufB, Wout, bout, out, n);
}

// Round 4
// 588.505 us; speedup vs baseline: 2.4072x; 1.0950x over previous
//
#include <hip/hip_runtime.h>
#include <hip/hip_bf16.h>

#define GN_EPS 1e-5f

// ---------------- CSR build ----------------
__global__ void k_degi(const int* __restrict__ dst, int* __restrict__ degi, int e) {
    int i = blockIdx.x * blockDim.x + threadIdx.x;
    if (i < e) atomicAdd(&degi[dst[i]], 1);
}

__global__ __launch_bounds__(1024) void k_scan(const int* __restrict__ degi,
                                               int* __restrict__ rowptr,
                                               int* __restrict__ cursor,
                                               float* __restrict__ dinv, int n) {
    __shared__ int wsum[16];
    __shared__ int carry_s;
    const int lane = threadIdx.x & 63;
    const int wid = threadIdx.x >> 6;
    if (threadIdx.x == 0) carry_s = 0;
    __syncthreads();
    for (int base = 0; base < n; base += 1024) {
        int i = base + threadIdx.x;
        int v = (i < n) ? degi[i] : 0;
        int x = v;
        #pragma unroll
        for (int off = 1; off < 64; off <<= 1) {
            int t = __shfl_up(x, off);
            if (lane >= off) x += t;
        }
        if (lane == 63) wsum[wid] = x;
        __syncthreads();
        if (wid == 0 && lane < 16) {
            int y = wsum[lane];
            #pragma unroll
            for (int off = 1; off < 16; off <<= 1) {
                int t = __shfl_up(y, off, 16);
                if (lane >= off) y += t;
            }
            wsum[lane] = y;
        }
        __syncthreads();
        int waveoff = (wid == 0) ? 0 : wsum[wid - 1];
        int incl = x + waveoff + carry_s;
        if (i < n) {
            int excl = incl - v;
            rowptr[i] = excl;
            cursor[i] = excl;
            dinv[i] = rsqrtf((float)(v + 1));
        }
        __syncthreads();
        if (threadIdx.x == 1023) carry_s = incl;
        __syncthreads();
    }
    if (threadIdx.x == 0) rowptr[n] = carry_s;
}

__global__ void k_fill(const int* __restrict__ src, const int* __restrict__ dst,
                       int* __restrict__ cursor, int* __restrict__ csr_src, int e) {
    int i = blockIdx.x * blockDim.x + threadIdx.x;
    if (i < e) {
        int d = dst[i];
        int pos = atomicAdd(&cursor[d], 1);
        csr_src[pos] = src[i];
    }
}

// ---------------- GEMM: Y[n,128] = f(X)[n,128] @ W[128,128] ----------------
// Column-split: block = 64 rows x 64 cols (blockIdx.y picks col half).
// sW = 32KB, sx = 33KB -> 65KB LDS -> 2 blocks/CU (8 waves/CU).
// f(X) = relu(X*cs + cb) when cs != nullptr (fused GraphNorm+ReLU).
#define TM 64
__global__ __launch_bounds__(256) void k_gemm128(const float* __restrict__ X,
                                                 const float* __restrict__ W,
                                                 float* __restrict__ Y,
                                                 const float* __restrict__ cs,
                                                 const float* __restrict__ cb,
                                                 int nrows) {
    __shared__ float sW[128 * 64];
    __shared__ float sx[TM * 129];
    const int t = threadIdx.x;
    const int c0 = blockIdx.y * 64;

    // load W cols [c0, c0+64): 128 rows x 16 float4
    for (int i = t; i < 128 * 16; i += 256) {
        int k = i >> 4;
        int f4 = i & 15;
        ((float4*)(sW + k * 64))[f4] = ((const float4*)(W + (size_t)k * 128 + c0))[f4];
    }
    // load X tile (64 rows x 128), stride 129
    const int row0 = blockIdx.x * TM;
    if (cs) {
        for (int i = t; i < TM * 32; i += 256) {
            int r = i >> 5, c4 = i & 31;
            int grow = row0 + r;
            float4 v = make_float4(0.f, 0.f, 0.f, 0.f);
            if (grow < nrows) v = ((const float4*)(X + (size_t)grow * 128))[c4];
            float4 s4 = ((const float4*)cs)[c4];
            float4 b4 = ((const float4*)cb)[c4];
            v.x = fmaxf(fmaf(v.x, s4.x, b4.x), 0.f);
            v.y = fmaxf(fmaf(v.y, s4.y, b4.y), 0.f);
            v.z = fmaxf(fmaf(v.z, s4.z, b4.z), 0.f);
            v.w = fmaxf(fmaf(v.w, s4.w, b4.w), 0.f);
            float* d = &sx[r * 129 + c4 * 4];
            d[0] = v.x; d[1] = v.y; d[2] = v.z; d[3] = v.w;
        }
    } else {
        for (int i = t; i < TM * 32; i += 256) {
            int r = i >> 5, c4 = i & 31;
            int grow = row0 + r;
            float4 v = make_float4(0.f, 0.f, 0.f, 0.f);
            if (grow < nrows) v = ((const float4*)(X + (size_t)grow * 128))[c4];
            float* d = &sx[r * 129 + c4 * 4];
            d[0] = v.x; d[1] = v.y; d[2] = v.z; d[3] = v.w;
        }
    }
    __syncthreads();

    const int tc = t & 15;   // col group: cols tc*4 .. tc*4+3 (of 64)
    const int tr = t >> 4;   // row group: rows tr*4 .. tr*4+3
    float acc[4][4] = {};
    #pragma unroll 4
    for (int k = 0; k < 128; ++k) {
        float4 w = *(const float4*)(sW + k * 64 + tc * 4);
        float x0 = sx[(tr * 4 + 0) * 129 + k];
        float x1 = sx[(tr * 4 + 1) * 129 + k];
        float x2 = sx[(tr * 4 + 2) * 129 + k];
        float x3 = sx[(tr * 4 + 3) * 129 + k];
        acc[0][0] += x0 * w.x; acc[0][1] += x0 * w.y; acc[0][2] += x0 * w.z; acc[0][3] += x0 * w.w;
        acc[1][0] += x1 * w.x; acc[1][1] += x1 * w.y; acc[1][2] += x1 * w.z; acc[1][3] += x1 * w.w;
        acc[2][0] += x2 * w.x; acc[2][1] += x2 * w.y; acc[2][2] += x2 * w.z; acc[2][3] += x2 * w.w;
        acc[3][0] += x3 * w.x; acc[3][1] += x3 * w.y; acc[3][2] += x3 * w.z; acc[3][3] += x3 * w.w;
    }
    #pragma unroll
    for (int i = 0; i < 4; ++i) {
        int grow = row0 + tr * 4 + i;
        if (grow >= nrows) continue;
        *(float4*)(Y + (size_t)grow * 128 + c0 + tc * 4) =
            make_float4(acc[i][0], acc[i][1], acc[i][2], acc[i][3]);
    }
}

// ---------------- pull-gather conv ----------------
__global__ __launch_bounds__(256) void k_gather(const float* __restrict__ H,
                                                float* __restrict__ O,
                                                const int* __restrict__ rowptr,
                                                const int* __restrict__ csr_src,
                                                const float* __restrict__ dinv,
                                                const float* __restrict__ bias, int n) {
    int node = blockIdx.x * 4 + (threadIdx.x >> 6);
    if (node >= n) return;
    int lane = threadIdx.x & 63;
    float di = dinv[node];
    float2 h = ((const float2*)(H + (size_t)node * 128))[lane];
    float2 b = ((const float2*)bias)[lane];
    float2 acc;
    acc.x = h.x * di * di + b.x;
    acc.y = h.y * di * di + b.y;
    int j = rowptr[node];
    const int end = rowptr[node + 1];
    for (; j + 3 < end; j += 4) {
        int s0 = csr_src[j], s1 = csr_src[j + 1], s2 = csr_src[j + 2], s3 = csr_src[j + 3];
        float n0 = dinv[s0] * di, n1 = dinv[s1] * di, n2 = dinv[s2] * di, n3 = dinv[s3] * di;
        float2 v0 = ((const float2*)(H + (size_t)s0 * 128))[lane];
        float2 v1 = ((const float2*)(H + (size_t)s1 * 128))[lane];
        float2 v2 = ((const float2*)(H + (size_t)s2 * 128))[lane];
        float2 v3 = ((const float2*)(H + (size_t)s3 * 128))[lane];
        acc.x += v0.x * n0; acc.y += v0.y * n0;
        acc.x += v1.x * n1; acc.y += v1.y * n1;
        acc.x += v2.x * n2; acc.y += v2.y * n2;
        acc.x += v3.x * n3; acc.y += v3.y * n3;
    }
    for (; j < end; ++j) {
        int s = csr_src[j];
        float nn = dinv[s] * di;
        float2 v = ((const float2*)(H + (size_t)s * 128))[lane];
        acc.x += v.x * nn; acc.y += v.y * nn;
    }
    ((float2*)(O + (size_t)node * 128))[lane] = acc;
}

// ---------------- GraphNorm stats ----------------
__global__ __launch_bounds__(256) void k_stats(const float* __restrict__ H,
                                               float* __restrict__ S, int n) {
    int c = threadIdx.x & 127;
    int half = threadIdx.x >> 7;
    float sum = 0.f, ss = 0.f;
    for (int r = blockIdx.x * 2 + half; r < n; r += gridDim.x * 2) {
        float v = H[(size_t)r * 128 + c];
        sum += v;
        ss += v * v;
    }
    __shared__ float ls[256], lss[256];
    ls[threadIdx.x] = sum;
    lss[threadIdx.x] = ss;
    __syncthreads();
    if (threadIdx.x < 128) {
        atomicAdd(&S[c],       ls[threadIdx.x] + ls[threadIdx.x + 128]);
        atomicAdd(&S[128 + c], lss[threadIdx.x] + lss[threadIdx.x + 128]);
    }
}

__global__ void k_finstats(const float* __restrict__ S,
                           const float* __restrict__ w, const float* __restrict__ b,
                           const float* __restrict__ alpha,
                           float* __restrict__ colscale, float* __restrict__ colshift,
                           int n) {
    int c = threadIdx.x;
    if (c >= 128) return;
    float inv_n = 1.0f / (float)n;
    float m = S[c] * inv_n;
    float eh2 = S[128 + c] * inv_n;
    float a = alpha[c];
    float var = eh2 - (2.0f * a - a * a) * m * m;
    float scale = rsqrtf(var + GN_EPS) * w[c];
    colscale[c] = scale;
    colshift[c] = b[c] - a * m * scale;
}

// ---------------- output projection ----------------
__global__ __launch_bounds__(256) void k_outproj(const float* __restrict__ H,
                                                 const float* __restrict__ Wo,
                                                 const float* __restrict__ bo,
                                                 float* __restrict__ out, int n) {
    int row = blockIdx.x * (blockDim.x >> 6) + (threadIdx.x >> 6);
    if (row >= n) return;
    int lane = threadIdx.x & 63;
    const float* hr = H + (size_t)row * 128;
    float h0 = hr[lane], h1 = hr[lane + 64];
    float a0 = h0 * Wo[2 * lane]     + h1 * Wo[2 * (lane + 64)];
    float a1 = h0 * Wo[2 * lane + 1] + h1 * Wo[2 * (lane + 64) + 1];
    #pragma unroll
    for (int off = 32; off; off >>= 1) {
        a0 += __shfl_down(a0, off);
        a1 += __shfl_down(a1, off);
    }
    if (lane == 0) {
        out[(size_t)row * 2]     = a0 + bo[0];
        out[(size_t)row * 2 + 1] = a1 + bo[1];
    }
}

extern "C" void kernel_launch(void* const* d_in, const int* in_sizes, int n_in,
                              void* d_out, int out_size, void* d_ws, size_t ws_size,
                              hipStream_t stream) {
    const float* x    = (const float*)d_in[0];
    const int*   ei   = (const int*)  d_in[1];
    const float* W1   = (const float*)d_in[2];
    const float* b1   = (const float*)d_in[3];
    const float* W2   = (const float*)d_in[4];
    const float* b2   = (const float*)d_in[5];
    const float* W3   = (const float*)d_in[6];
    const float* b3   = (const float*)d_in[7];
    const float* gn1w = (const float*)d_in[8];
    const float* gn1b = (const float*)d_in[9];
    const float* gn1a = (const float*)d_in[10];
    const float* gn2w = (const float*)d_in[11];
    const float* gn2b = (const float*)d_in[12];
    const float* gn2a = (const float*)d_in[13];
    const float* Wout = (const float*)d_in[14];
    const float* bout = (const float*)d_in[15];
    float* out = (float*)d_out;

    const int n = in_sizes[0] / 128;
    const int e = in_sizes[1] / 2;
    const int* srcI = ei;
    const int* dstI = ei + e;

    float* bufA     = (float*)d_ws;                      // n*128
    float* bufB     = bufA + (size_t)n * 128;            // n*128
    float* dinv     = bufB + (size_t)n * 128;            // n
    float* S        = dinv + n;                          // 256
    float* colscale = S + 256;                           // 128
    float* colshift = colscale + 128;                    // 128
    int*   degi     = (int*)(colshift + 128);            // n
    int*   rowptr   = degi + n;                          // n+1
    int*   cursor   = rowptr + n + 1;                    // n
    int*   csr_src  = cursor + n;                        // e

    // ---- CSR build ----
    hipMemsetAsync(degi, 0, (size_t)n * sizeof(int), stream);
    k_degi<<<(e + 255) / 256, 256, 0, stream>>>(dstI, degi, e);
    k_scan<<<1, 1024, 0, stream>>>(degi, rowptr, cursor, dinv, n);
    k_fill<<<(e + 255) / 256, 256, 0, stream>>>(srcI, dstI, cursor, csr_src, e);

    const dim3 gemmGrid((n + TM - 1) / TM, 2);

    // layer 1 (no input norm)
    k_gemm128<<<gemmGrid, 256, 0, stream>>>(x, W1, bufA, nullptr, nullptr, n);
    k_gather<<<(n + 3) / 4, 256, 0, stream>>>(bufA, bufB, rowptr, csr_src, dinv, b1, n);
    hipMemsetAsync(S, 0, 256 * sizeof(float), stream);
    k_stats<<<512, 256, 0, stream>>>(bufB, S, n);
    k_finstats<<<1, 128, 0, stream>>>(S, gn1w, gn1b, gn1a, colscale, colshift, n);

    // layer 2 (norm+relu fused into GEMM input load)
    k_gemm128<<<gemmGrid, 256, 0, stream>>>(bufB, W2, bufA, colscale, colshift, n);
    k_gather<<<(n + 3) / 4, 256, 0, stream>>>(bufA, bufB, rowptr, csr_src, dinv, b2, n);
    hipMemsetAsync(S, 0, 256 * sizeof(float), stream);
    k_stats<<<512, 256, 0, stream>>>(bufB, S, n);
    k_finstats<<<1, 128, 0, stream>>>(S, gn2w, gn2b, gn2a, colscale, colshift, n);

    // layer 3 + projection
    k_gemm128<<<gemmGrid, 256, 0, stream>>>(bufB, W3, bufA, colscale, colshift, n);
    k_gather<<<(n + 3) / 4, 256, 0, stream>>>(bufA, bufB, rowptr, csr_src, dinv, b3, n);
    k_outproj<<<(n + 3) / 4, 256, 0, stream>>>(bufB, Wout, bout, out, n);
}

// Round 5
// 518.397 us; speedup vs baseline: 2.7327x; 1.1352x over previous
//
#include <hip/hip_runtime.h>
#include <hip/hip_bf16.h>

#define GN_EPS 1e-5f

__device__ __forceinline__ unsigned short f2bf(float f) {
    unsigned u = __float_as_uint(f);
    u += 0x7fffu + ((u >> 16) & 1u);   // round-to-nearest-even
    return (unsigned short)(u >> 16);
}

// ---------------- CSR build ----------------
__global__ void k_degi(const int* __restrict__ dst, int* __restrict__ degi, int e) {
    int i = blockIdx.x * blockDim.x + threadIdx.x;
    if (i < e) atomicAdd(&degi[dst[i]], 1);
}

// single-block scan, 4 elements/thread
__global__ __launch_bounds__(1024) void k_scan(const int* __restrict__ degi,
                                               int* __restrict__ rowptr,
                                               int* __restrict__ cursor,
                                               float* __restrict__ dinv, int n) {
    __shared__ int wsum[16];
    __shared__ int carry_s;
    const int lane = threadIdx.x & 63;
    const int wid = threadIdx.x >> 6;
    if (threadIdx.x == 0) carry_s = 0;
    __syncthreads();
    for (int base = 0; base < n; base += 4096) {
        int i = base + threadIdx.x * 4;
        int v0 = (i     < n) ? degi[i]     : 0;
        int v1 = (i + 1 < n) ? degi[i + 1] : 0;
        int v2 = (i + 2 < n) ? degi[i + 2] : 0;
        int v3 = (i + 3 < n) ? degi[i + 3] : 0;
        int s = v0 + v1 + v2 + v3;
        int x = s;
        #pragma unroll
        for (int off = 1; off < 64; off <<= 1) {
            int t = __shfl_up(x, off);
            if (lane >= off) x += t;
        }
        if (lane == 63) wsum[wid] = x;
        __syncthreads();
        if (wid == 0 && lane < 16) {
            int y = wsum[lane];
            #pragma unroll
            for (int off = 1; off < 16; off <<= 1) {
                int t = __shfl_up(y, off, 16);
                if (lane >= off) y += t;
            }
            wsum[lane] = y;
        }
        __syncthreads();
        int waveoff = (wid == 0) ? 0 : wsum[wid - 1];
        int incl = x + waveoff + carry_s;
        int e0 = incl - s;
        int e1 = e0 + v0, e2 = e1 + v1, e3 = e2 + v2;
        if (i < n)     { rowptr[i]     = e0; cursor[i]     = e0; dinv[i]     = rsqrtf((float)(v0 + 1)); }
        if (i + 1 < n) { rowptr[i + 1] = e1; cursor[i + 1] = e1; dinv[i + 1] = rsqrtf((float)(v1 + 1)); }
        if (i + 2 < n) { rowptr[i + 2] = e2; cursor[i + 2] = e2; dinv[i + 2] = rsqrtf((float)(v2 + 1)); }
        if (i + 3 < n) { rowptr[i + 3] = e3; cursor[i + 3] = e3; dinv[i + 3] = rsqrtf((float)(v3 + 1)); }
        __syncthreads();
        if (threadIdx.x == 1023) carry_s = incl;
        __syncthreads();
    }
    if (threadIdx.x == 0) rowptr[n] = carry_s;
}

__global__ void k_fill(const int* __restrict__ src, const int* __restrict__ dst,
                       int* __restrict__ cursor, int* __restrict__ csr_src, int e) {
    int i = blockIdx.x * blockDim.x + threadIdx.x;
    if (i < e) {
        int d = dst[i];
        int pos = atomicAdd(&cursor[d], 1);
        csr_src[pos] = src[i];
    }
}

// ---------------- GEMM: Ybf16[n,128] = f(X)[n,128] @ W[128,128] ----------------
// Column-split: block = 64 rows x 64 cols. sW 32KB + sx 33KB -> 2 blocks/CU.
// f(X) = relu(X*cs + cb) when cs != nullptr. Output stored as bf16 for the gather.
#define TM 64
__global__ __launch_bounds__(256) void k_gemm128(const float* __restrict__ X,
                                                 const float* __restrict__ W,
                                                 unsigned short* __restrict__ Y,
                                                 const float* __restrict__ cs,
                                                 const float* __restrict__ cb,
                                                 int nrows) {
    __shared__ float sW[128 * 64];
    __shared__ float sx[TM * 129];
    const int t = threadIdx.x;
    const int c0 = blockIdx.y * 64;

    for (int i = t; i < 128 * 16; i += 256) {
        int k = i >> 4;
        int f4 = i & 15;
        ((float4*)(sW + k * 64))[f4] = ((const float4*)(W + (size_t)k * 128 + c0))[f4];
    }
    const int row0 = blockIdx.x * TM;
    if (cs) {
        for (int i = t; i < TM * 32; i += 256) {
            int r = i >> 5, c4 = i & 31;
            int grow = row0 + r;
            float4 v = make_float4(0.f, 0.f, 0.f, 0.f);
            if (grow < nrows) v = ((const float4*)(X + (size_t)grow * 128))[c4];
            float4 s4 = ((const float4*)cs)[c4];
            float4 b4 = ((const float4*)cb)[c4];
            v.x = fmaxf(fmaf(v.x, s4.x, b4.x), 0.f);
            v.y = fmaxf(fmaf(v.y, s4.y, b4.y), 0.f);
            v.z = fmaxf(fmaf(v.z, s4.z, b4.z), 0.f);
            v.w = fmaxf(fmaf(v.w, s4.w, b4.w), 0.f);
            float* d = &sx[r * 129 + c4 * 4];
            d[0] = v.x; d[1] = v.y; d[2] = v.z; d[3] = v.w;
        }
    } else {
        for (int i = t; i < TM * 32; i += 256) {
            int r = i >> 5, c4 = i & 31;
            int grow = row0 + r;
            float4 v = make_float4(0.f, 0.f, 0.f, 0.f);
            if (grow < nrows) v = ((const float4*)(X + (size_t)grow * 128))[c4];
            float* d = &sx[r * 129 + c4 * 4];
            d[0] = v.x; d[1] = v.y; d[2] = v.z; d[3] = v.w;
        }
    }
    __syncthreads();

    const int tc = t & 15;
    const int tr = t >> 4;
    float acc[4][4] = {};
    #pragma unroll 4
    for (int k = 0; k < 128; ++k) {
        float4 w = *(const float4*)(sW + k * 64 + tc * 4);
        float x0 = sx[(tr * 4 + 0) * 129 + k];
        float x1 = sx[(tr * 4 + 1) * 129 + k];
        float x2 = sx[(tr * 4 + 2) * 129 + k];
        float x3 = sx[(tr * 4 + 3) * 129 + k];
        acc[0][0] += x0 * w.x; acc[0][1] += x0 * w.y; acc[0][2] += x0 * w.z; acc[0][3] += x0 * w.w;
        acc[1][0] += x1 * w.x; acc[1][1] += x1 * w.y; acc[1][2] += x1 * w.z; acc[1][3] += x1 * w.w;
        acc[2][0] += x2 * w.x; acc[2][1] += x2 * w.y; acc[2][2] += x2 * w.z; acc[2][3] += x2 * w.w;
        acc[3][0] += x3 * w.x; acc[3][1] += x3 * w.y; acc[3][2] += x3 * w.z; acc[3][3] += x3 * w.w;
    }
    #pragma unroll
    for (int i = 0; i < 4; ++i) {
        int grow = row0 + tr * 4 + i;
        if (grow >= nrows) continue;
        ushort4 o;
        o.x = f2bf(acc[i][0]); o.y = f2bf(acc[i][1]);
        o.z = f2bf(acc[i][2]); o.w = f2bf(acc[i][3]);
        *(ushort4*)(Y + (size_t)grow * 128 + c0 + tc * 4) = o;
    }
}

// ---------------- pull-gather conv (bf16 input, fp32 output) ----------------
// One wave per node. H rows are bf16 (256B); lane reads one uint (2 bf16) per row.
__global__ __launch_bounds__(256) void k_gather(const unsigned short* __restrict__ H,
                                                float* __restrict__ O,
                                                const int* __restrict__ rowptr,
                                                const int* __restrict__ csr_src,
                                                const float* __restrict__ dinv,
                                                const float* __restrict__ bias, int n) {
    int node = blockIdx.x * 4 + (threadIdx.x >> 6);
    if (node >= n) return;
    int lane = threadIdx.x & 63;
    const unsigned* H2 = (const unsigned*)H;
    float di = dinv[node];
    unsigned hu = H2[(size_t)node * 64 + lane];
    float2 b = ((const float2*)bias)[lane];
    float2 acc;
    acc.x = __uint_as_float(hu << 16)          * di * di + b.x;
    acc.y = __uint_as_float(hu & 0xffff0000u)  * di * di + b.y;
    int j = rowptr[node];
    const int end = rowptr[node + 1];
    for (; j + 7 < end; j += 8) {
        int s[8];
        #pragma unroll
        for (int q = 0; q < 8; ++q) s[q] = csr_src[j + q];
        unsigned u[8];
        float nr[8];
        #pragma unroll
        for (int q = 0; q < 8; ++q) {
            u[q] = H2[(size_t)s[q] * 64 + lane];
            nr[q] = dinv[s[q]] * di;
        }
        #pragma unroll
        for (int q = 0; q < 8; ++q) {
            acc.x += __uint_as_float(u[q] << 16)         * nr[q];
            acc.y += __uint_as_float(u[q] & 0xffff0000u) * nr[q];
        }
    }
    for (; j < end; ++j) {
        int s = csr_src[j];
        float nn = dinv[s] * di;
        unsigned u = H2[(size_t)s * 64 + lane];
        acc.x += __uint_as_float(u << 16)         * nn;
        acc.y += __uint_as_float(u & 0xffff0000u) * nn;
    }
    ((float2*)(O + (size_t)node * 128))[lane] = acc;
}

// ---------------- GraphNorm stats ----------------
__global__ __launch_bounds__(256) void k_stats(const float* __restrict__ H,
                                               float* __restrict__ S, int n) {
    int c = threadIdx.x & 127;
    int half = threadIdx.x >> 7;
    float sum = 0.f, ss = 0.f;
    for (int r = blockIdx.x * 2 + half; r < n; r += gridDim.x * 2) {
        float v = H[(size_t)r * 128 + c];
        sum += v;
        ss += v * v;
    }
    __shared__ float ls[256], lss[256];
    ls[threadIdx.x] = sum;
    lss[threadIdx.x] = ss;
    __syncthreads();
    if (threadIdx.x < 128) {
        atomicAdd(&S[c],       ls[threadIdx.x] + ls[threadIdx.x + 128]);
        atomicAdd(&S[128 + c], lss[threadIdx.x] + lss[threadIdx.x + 128]);
    }
}

__global__ void k_finstats(const float* __restrict__ S,
                           const float* __restrict__ w, const float* __restrict__ b,
                           const float* __restrict__ alpha,
                           float* __restrict__ colscale, float* __restrict__ colshift,
                           int n) {
    int c = threadIdx.x;
    if (c >= 128) return;
    float inv_n = 1.0f / (float)n;
    float m = S[c] * inv_n;
    float eh2 = S[128 + c] * inv_n;
    float a = alpha[c];
    float var = eh2 - (2.0f * a - a * a) * m * m;
    float scale = rsqrtf(var + GN_EPS) * w[c];
    colscale[c] = scale;
    colshift[c] = b[c] - a * m * scale;
}

// ---------------- output projection ----------------
__global__ __launch_bounds__(256) void k_outproj(const float* __restrict__ H,
                                                 const float* __restrict__ Wo,
                                                 const float* __restrict__ bo,
                                                 float* __restrict__ out, int n) {
    int row = blockIdx.x * (blockDim.x >> 6) + (threadIdx.x >> 6);
    if (row >= n) return;
    int lane = threadIdx.x & 63;
    const float* hr = H + (size_t)row * 128;
    float h0 = hr[lane], h1 = hr[lane + 64];
    float a0 = h0 * Wo[2 * lane]     + h1 * Wo[2 * (lane + 64)];
    float a1 = h0 * Wo[2 * lane + 1] + h1 * Wo[2 * (lane + 64) + 1];
    #pragma unroll
    for (int off = 32; off; off >>= 1) {
        a0 += __shfl_down(a0, off);
        a1 += __shfl_down(a1, off);
    }
    if (lane == 0) {
        out[(size_t)row * 2]     = a0 + bo[0];
        out[(size_t)row * 2 + 1] = a1 + bo[1];
    }
}

extern "C" void kernel_launch(void* const* d_in, const int* in_sizes, int n_in,
                              void* d_out, int out_size, void* d_ws, size_t ws_size,
                              hipStream_t stream) {
    const float* x    = (const float*)d_in[0];
    const int*   ei   = (const int*)  d_in[1];
    const float* W1   = (const float*)d_in[2];
    const float* b1   = (const float*)d_in[3];
    const float* W2   = (const float*)d_in[4];
    const float* b2   = (const float*)d_in[5];
    const float* W3   = (const float*)d_in[6];
    const float* b3   = (const float*)d_in[7];
    const float* gn1w = (const float*)d_in[8];
    const float* gn1b = (const float*)d_in[9];
    const float* gn1a = (const float*)d_in[10];
    const float* gn2w = (const float*)d_in[11];
    const float* gn2b = (const float*)d_in[12];
    const float* gn2a = (const float*)d_in[13];
    const float* Wout = (const float*)d_in[14];
    const float* bout = (const float*)d_in[15];
    float* out = (float*)d_out;

    const int n = in_sizes[0] / 128;
    const int e = in_sizes[1] / 2;
    const int* srcI = ei;
    const int* dstI = ei + e;

    float* bufB     = (float*)d_ws;                      // n*128 fp32 (gather out)
    unsigned short* bufH = (unsigned short*)(bufB + (size_t)n * 128); // n*128 bf16 (gemm out)
    float* dinv     = (float*)(bufH + (size_t)n * 128);  // n
    float* S        = dinv + n;                          // 256
    float* colscale = S + 256;                           // 128
    float* colshift = colscale + 128;                    // 128
    int*   degi     = (int*)(colshift + 128);            // n
    int*   rowptr   = degi + n;                          // n+1
    int*   cursor   = rowptr + n + 1;                    // n
    int*   csr_src  = cursor + n;                        // e

    // ---- CSR build ----
    hipMemsetAsync(degi, 0, (size_t)n * sizeof(int), stream);
    k_degi<<<(e + 255) / 256, 256, 0, stream>>>(dstI, degi, e);
    k_scan<<<1, 1024, 0, stream>>>(degi, rowptr, cursor, dinv, n);
    k_fill<<<(e + 255) / 256, 256, 0, stream>>>(srcI, dstI, cursor, csr_src, e);

    const dim3 gemmGrid((n + TM - 1) / TM, 2);

    // layer 1
    k_gemm128<<<gemmGrid, 256, 0, stream>>>(x, W1, bufH, nullptr, nullptr, n);
    k_gather<<<(n + 3) / 4, 256, 0, stream>>>(bufH, bufB, rowptr, csr_src, dinv, b1, n);
    hipMemsetAsync(S, 0, 256 * sizeof(float), stream);
    k_stats<<<512, 256, 0, stream>>>(bufB, S, n);
    k_finstats<<<1, 128, 0, stream>>>(S, gn1w, gn1b, gn1a, colscale, colshift, n);

    // layer 2
    k_gemm128<<<gemmGrid, 256, 0, stream>>>(bufB, W2, bufH, colscale, colshift, n);
    k_gather<<<(n + 3) / 4, 256, 0, stream>>>(bufH, bufB, rowptr, csr_src, dinv, b2, n);
    hipMemsetAsync(S, 0, 256 * sizeof(float), stream);
    k_stats<<<512, 256, 0, stream>>>(bufB, S, n);
    k_finstats<<<1, 128, 0, stream>>>(S, gn2w, gn2b, gn2a, colscale, colshift, n);

    // layer 3 + projection
    k_gemm128<<<gemmGrid, 256, 0, stream>>>(bufB, W3, bufH, colscale, colshift, n);
    k_gather<<<(n + 3) / 4, 256, 0, stream>>>(bufH, bufB, rowptr, csr_src, dinv, b3, n);
    k_outproj<<<(n + 3) / 4, 256, 0, stream>>>(bufB, Wout, bout, out, n);
}